// Round 10
// baseline (54.370 us; speedup 1.0000x reference)
//
#include <hip/hip_runtime.h>
#include <stdint.h>

#define B 4
#define N 16384
#define S 2048
#define C 64
#define K 64
#define OC 66
#define R2 0.01f
#define NXCD 8

typedef float f32x4 __attribute__((ext_vector_type(4)));

// ---------------------------------------------------------------------------
// Kernel 1 (prep, heterogeneous grid):
//   blocks [0, 1024):    transpose features (B,C,N) -> ft (B,N,C)
//   blocks [1024, 3072): ball-query scan (one wave/query) -> idx[B*S][K]
//                        + output channels 0,1 (grouped_xyz)
// Scan compute overlaps transpose's HBM streaming instead of serializing.
// ---------------------------------------------------------------------------
__global__ __launch_bounds__(256) void prep_kernel(const float* __restrict__ f,
                                                   const float* __restrict__ xyz,
                                                   const float* __restrict__ new_xyz,
                                                   const int* __restrict__ pointsnum,
                                                   float* __restrict__ ft,
                                                   int* __restrict__ idx,
                                                   float* __restrict__ out) {
    __shared__ float tile[64 * 65];
    __shared__ int   s_idx[4][K];

    const int t = threadIdx.x;

    if (blockIdx.x < 1024) {
        // ---------------- transpose path ----------------
        const int n0 = (blockIdx.x & 255) * 64;
        const int b  = blockIdx.x >> 8;

        const int nl = t & 63, cl = t >> 6;
        #pragma unroll
        for (int cc = cl; cc < 64; cc += 4) {
            tile[cc * 65 + nl] = __builtin_nontemporal_load(&f[((size_t)b * C + cc) * N + n0 + nl]);
        }
        __syncthreads();

        const int cl2 = t & 63, nl2 = t >> 6;
        #pragma unroll
        for (int nn = nl2; nn < 64; nn += 4) {
            ft[((size_t)b * N + n0 + nn) * C + cl2] = tile[cl2 * 65 + nn];
        }
        return;
    }

    // ---------------- scan path (one wave per query) ----------------
    const int lane = t & 63;
    const int wu   = __builtin_amdgcn_readfirstlane(t >> 6);
    const int q0   = (int)(blockIdx.x - 1024) * 4;
    const int b    = q0 >> 11;             // / S (S=2048)
    const int q    = q0 + wu;
    const int s    = (q0 & (S - 1)) + wu;

    const float qx = new_xyz[(size_t)q * 2 + 0];
    const float qy = new_xyz[(size_t)q * 2 + 1];
    const float* __restrict__ xb = xyz + (size_t)b * N * 2;

    int pn = pointsnum[b];
    pn = pn < 0 ? 0 : (pn > N ? N : pn);
    int cnt = 0;
    float2 p[4], pf[4];
    #pragma unroll
    for (int u = 0; u < 4; ++u) {
        const int i  = u * 64 + lane;
        const int ic = i < N ? i : N - 1;
        p[u] = *(const float2*)&xb[(size_t)ic * 2];
    }
    for (int base = 0; base < pn && cnt < K; base += 256) {
        #pragma unroll
        for (int u = 0; u < 4; ++u) {       // prefetch next super-chunk
            const int i  = base + 256 + u * 64 + lane;
            const int ic = i < N ? i : N - 1;
            pf[u] = *(const float2*)&xb[(size_t)ic * 2];
        }
        #pragma unroll
        for (int u = 0; u < 4; ++u) {
            const int i = base + u * 64 + lane;
            bool ok = false;
            if (i < pn) {
                // match numpy f32 rounding exactly: no FMA contraction
                const float dx = __fsub_rn(qx, p[u].x);
                const float dy = __fsub_rn(qy, p[u].y);
                const float d2 = __fadd_rn(__fmul_rn(dx, dx), __fmul_rn(dy, dy));
                ok = d2 < R2;
            }
            const unsigned long long m = __ballot(ok);
            if (ok) {
                const int pos = cnt + __popcll(m & ((1ull << lane) - 1ull));
                if (pos < K) s_idx[wu][pos] = i;
            }
            cnt += __popcll(m);
        }
        #pragma unroll
        for (int u = 0; u < 4; ++u) p[u] = pf[u];
    }
    const int found = cnt < K ? cnt : K;
    const int first = (found > 0) ? s_idx[wu][0] : 0;   // pad value (0 if none)
    const int id    = (lane < found) ? s_idx[wu][lane] : first;

    idx[(size_t)q * K + lane] = id;                     // coalesced 256B

    // channels 0,1: grouped_xyz = xyz[id] - new_xyz[s]
    const size_t SK = (size_t)S * K;
    const float2 pxy = *(const float2*)&xb[(size_t)id * 2];
    float* ob = out + ((size_t)b * OC) * SK + (size_t)s * K;
    ob[lane]      = pxy.x - qx;
    ob[SK + lane] = pxy.y - qy;
}

// ---------------------------------------------------------------------------
// Kernel 2 (gather): pure streaming, no LDS, no barriers. One wave/query,
// 4 queries/block, XCD swizzle. Gather: 4 lanes per point-row (16 rows x
// 64B line per instr, every line touched once). Store DIRECTLY from gather
// regs: each store instr = 4 channel-planes x 16 consecutive k = 4x64B
// fully-utilized runs. Stores begin immediately -> issue hides under the
// HBM write drain.
// ---------------------------------------------------------------------------
__global__ __launch_bounds__(256) void gather2_kernel(const float* __restrict__ ft,
                                                      const int* __restrict__ idx,
                                                      float* __restrict__ out) {
    const int t    = threadIdx.x;
    const int lane = t & 63;
    const int wu   = __builtin_amdgcn_readfirstlane(t >> 6);

    // bijective XCD swizzle: nwg = 2048, 2048 % 8 == 0
    const int nwg = (B * S) / 4;
    const int bid = blockIdx.x;
    const int swz = (bid & (NXCD - 1)) * (nwg / NXCD) + (bid >> 3);

    const int q0 = swz * 4;
    const int b  = q0 >> 11;
    const int q  = q0 + wu;
    const int s  = (q0 & (S - 1)) + wu;

    const int kk = lane >> 2;              // point sub-index 0..15
    const int c2 = lane & 3;               // float4 slot within 16-ch chunk

    int ids[4];
    #pragma unroll
    for (int g = 0; g < 4; ++g) {
        ids[g] = idx[(size_t)q * K + g * 16 + kk];      // 16 ints, broadcast x4
    }

    const float* __restrict__ ftb = ft + (size_t)b * N * C;
    const size_t SK = (size_t)S * K;
    float* ob = out + ((size_t)b * OC) * SK + (size_t)s * K;

    #pragma unroll
    for (int cc = 0; cc < 4; ++cc) {       // 16-channel chunks
        #pragma unroll
        for (int g = 0; g < 4; ++g) {
            const f32x4 v = *(const f32x4*)&ftb[(size_t)ids[g] * C + cc * 16 + c2 * 4];
            const int k = g * 16 + kk;
            const int c = 2 + cc * 16 + c2 * 4;
            ob[(size_t)(c + 0) * SK + k] = v.x;
            ob[(size_t)(c + 1) * SK + k] = v.y;
            ob[(size_t)(c + 2) * SK + k] = v.z;
            ob[(size_t)(c + 3) * SK + k] = v.w;
        }
    }
}

// ---------------------------------------------------------------------------
// Fallback (tiny ws): fused kernel gathering directly from (B,C,N) feat.
// ---------------------------------------------------------------------------
__global__ __launch_bounds__(256) void qag_fallback(const float* __restrict__ xyz,
                                                    const float* __restrict__ new_xyz,
                                                    const float* __restrict__ feat,
                                                    const int* __restrict__ pointsnum,
                                                    float* __restrict__ out) {
    __shared__ int s_idx[4][K];

    const int t    = threadIdx.x;
    const int lane = t & 63;
    const int wu   = __builtin_amdgcn_readfirstlane(t >> 6);
    const int q0   = blockIdx.x * 4;
    const int b    = q0 >> 11;
    const int q    = q0 + wu;
    const int s    = (q0 & (S - 1)) + wu;

    const float qx = new_xyz[(size_t)q * 2 + 0];
    const float qy = new_xyz[(size_t)q * 2 + 1];
    const float* __restrict__ xb = xyz + (size_t)b * N * 2;

    int pn = pointsnum[b];
    pn = pn < 0 ? 0 : (pn > N ? N : pn);
    int cnt = 0;
    for (int base = 0; base < pn && cnt < K; base += 256) {
        float2 p[4];
        #pragma unroll
        for (int u = 0; u < 4; ++u) {
            int i  = base + u * 64 + lane;
            int ic = i < N ? i : N - 1;
            p[u] = *(const float2*)&xb[(size_t)ic * 2];
        }
        #pragma unroll
        for (int u = 0; u < 4; ++u) {
            const int i = base + u * 64 + lane;
            bool ok = false;
            if (i < pn) {
                const float dx = __fsub_rn(qx, p[u].x);
                const float dy = __fsub_rn(qy, p[u].y);
                const float d2 = __fadd_rn(__fmul_rn(dx, dx), __fmul_rn(dy, dy));
                ok = d2 < R2;
            }
            const unsigned long long mm = __ballot(ok);
            if (ok) {
                const int pos = cnt + __popcll(mm & ((1ull << lane) - 1ull));
                if (pos < K) s_idx[wu][pos] = i;
            }
            cnt += __popcll(mm);
        }
    }
    const int found = cnt < K ? cnt : K;
    const int first = (found > 0) ? s_idx[wu][0] : 0;
    const int id    = (lane < found) ? s_idx[wu][lane] : first;

    const size_t SK = (size_t)S * K;
    const float2 pxy = *(const float2*)&xb[(size_t)id * 2];
    float* ob = out + ((size_t)b * OC) * SK + (size_t)s * K;
    ob[lane]      = pxy.x - qx;
    ob[SK + lane] = pxy.y - qy;

    const float* __restrict__ fb = feat + (size_t)b * C * N;
    for (int c = 0; c < C; ++c) {
        ob[(size_t)(2 + c) * SK + lane] = fb[(size_t)c * N + id];
    }
}

extern "C" void kernel_launch(void* const* d_in, const int* in_sizes, int n_in,
                              void* d_out, int out_size, void* d_ws, size_t ws_size,
                              hipStream_t stream) {
    const float* xyz       = (const float*)d_in[0];
    const float* new_xyz   = (const float*)d_in[1];
    const float* feat      = (const float*)d_in[2];
    const int*   pointsnum = (const int*)d_in[3];
    float*       out       = (float*)d_out;

    const size_t ft_bytes  = (size_t)B * N * C * sizeof(float);   // 16.8 MB
    const size_t idx_bytes = (size_t)B * S * K * sizeof(int);     //  2.1 MB

    if (ws_size >= ft_bytes + idx_bytes) {
        float* ft  = (float*)d_ws;
        int*   idx = (int*)((char*)d_ws + ft_bytes);
        prep_kernel<<<1024 + B * S / 4, 256, 0, stream>>>(feat, xyz, new_xyz, pointsnum, ft, idx, out);
        gather2_kernel<<<B * S / 4, 256, 0, stream>>>(ft, idx, out);
    } else {
        qag_fallback<<<B * S / 4, 256, 0, stream>>>(xyz, new_xyz, feat, pointsnum, out);
    }
}